// Round 3
// baseline (127.908 us; speedup 1.0000x reference)
//
#include <hip/hip_runtime.h>

// lambda-return reverse scan, T=16 rows x B=524288 cols, fp32.
//
// v3 (resubmit -- round 2 was an infra failure, container died twice;
// the float4 hypothesis is still untested).
//
// v3: float4 (16 B/lane) instead of float2. v1 (full 46-load flood) and
// v2 (rolling 4-row window) timed IDENTICALLY (~40us kernel, ~3.2 TB/s) ->
// load-issue structure is not the limiter. The measured 6.3 TB/s ceiling
// (m13) is a float4 copy; G13 says 16 B/lane is the coalescing sweet spot.
// This round tests vector width as the single variable.
//
// Shape: one thread per 4 columns. Bv4 = 131072 -> grid 512 x 256
// (8 waves/CU, 2/SIMD). In-flight per CU at steady state:
// ~12 float4 loads/wave x 1 KB x 8 waves = 96 KB >> ~10 KB latency-BW
// product, so 2 waves/SIMD still fully hides HBM latency.
// __launch_bounds__(256,4) caps VGPR at 128: window (~70 regs) fits,
// and the compiler cannot re-hoist into a 184-reg full flood.

constexpr int   T_STEPS = 16;
constexpr float LAM     = 0.95f;
constexpr int   W       = 4;   // rows in flight (ring buffer, power of 2)

typedef float f32x4 __attribute__((ext_vector_type(4)));

__global__ __launch_bounds__(256, 4)
void ImagBehavior_67284957659345_kernel(const f32x4* __restrict__ reward,
                                        const f32x4* __restrict__ value,
                                        const f32x4* __restrict__ discount,
                                        f32x4* __restrict__ out,
                                        int Bv /* = B/4 */) {
    int idx = blockIdx.x * blockDim.x + threadIdx.x;
    if (idx >= Bv) return;

    f32x4 r[W], d[W], v[W];

    // bootstrap: acc = value[15]
    f32x4 acc = value[(T_STEPS - 1) * Bv + idx];

    // prologue: issue rows 14..11 (r,d,v each)
#pragma unroll
    for (int j = 0; j < W; ++j) {
        const int t = T_STEPS - 2 - j;  // 14..11
        r[t & (W - 1)] = reward[t * Bv + idx];
        d[t & (W - 1)] = discount[t * Bv + idx];
        v[t & (W - 1)] = value[t * Bv + idx];
    }

    f32x4 v_next = acc;  // v[t+1] for step t=14 is v[15] == bootstrap

#pragma unroll
    for (int t = T_STEPS - 2; t >= 0; --t) {
        const int s = t & (W - 1);
        const f32x4 rt    = r[s];
        const f32x4 dt    = d[s];
        const f32x4 vt1   = v_next;  // v[t+1]
        const f32x4 vtcur = v[s];    // v[t], needed at step t-1

        // steady-state issue: row t-W into the freed slot, before this
        // step's compute so it stays in flight across it.
        const int tp = t - W;
        if (tp >= 0) {
            r[tp & (W - 1)] = reward[tp * Bv + idx];
            d[tp & (W - 1)] = discount[tp * Bv + idx];
            if (tp >= 1) v[tp & (W - 1)] = value[tp * Bv + idx];  // v[0] never read
        }

        // elementwise on ext_vector: same per-element FMA order as v2
        acc = rt + dt * (LAM * acc + (1.0f - LAM) * vt1);
        out[t * Bv + idx] = acc;  // fire-and-forget store

        v_next = vtcur;
    }
}

extern "C" void kernel_launch(void* const* d_in, const int* in_sizes, int n_in,
                              void* d_out, int out_size, void* d_ws, size_t ws_size,
                              hipStream_t stream) {
    const f32x4* reward   = (const f32x4*)d_in[0];
    const f32x4* value    = (const f32x4*)d_in[1];
    const f32x4* discount = (const f32x4*)d_in[2];
    f32x4*       out      = (f32x4*)d_out;

    const int B   = in_sizes[0] / T_STEPS;  // 524288
    const int Bv4 = B / 4;                  // 131072 float4 columns

    const int block = 256;
    const int grid  = (Bv4 + block - 1) / block;  // 512 blocks

    ImagBehavior_67284957659345_kernel<<<grid, block, 0, stream>>>(
        reward, value, discount, out, Bv4);
}